// Round 6
// baseline (155.330 us; speedup 1.0000x reference)
//
#include <hip/hip_runtime.h>

// MultiHeadGraphAttention: B=8, N=1024, IN=OUT=256, H=8, d_k=32
// prep(X/W cvt) -> QKV gemm (bf16 MFMA, Q pre-scaled by log2e/sqrt(dk))
// -> fused masked attention: fixed-max softmax (p = exp2(s - ds*log2e*D),
//    masked -> exactly 0) is associative over keys, so keys are split 4-way
//    across the block's waves and partial (o, l) are LDS-reduced at the end.
// -> out proj.

typedef __bf16 bf16x8 __attribute__((ext_vector_type(8)));
typedef __bf16 bf16x4 __attribute__((ext_vector_type(4)));
typedef float f32x4 __attribute__((ext_vector_type(4)));
typedef int i32x4 __attribute__((ext_vector_type(4)));

#define DEV static __device__ __forceinline__

#define LOG2E 1.4426950408889634f
#define QSCALE 0.2550351062f   // (1/sqrt(32)) * log2(e)

DEV unsigned short f2bf(float f) {   // RNE f32 -> bf16 bits
  union { float f; unsigned u; } x; x.f = f;
  unsigned r = x.u + 0x7fffu + ((x.u >> 16) & 1u);
  return (unsigned short)(r >> 16);
}

DEV f32x4 mfma16(bf16x8 a, bf16x8 b, f32x4 c) {
  return __builtin_amdgcn_mfma_f32_16x16x32_bf16(a, b, c, 0, 0, 0);
}

DEV bf16x8 ldfrag(const unsigned short* p) {
  return *reinterpret_cast<const bf16x8*>(p);
}

// ---------------- prep: X f32->bf16 ; W_{q,k,v,o} -> bf16 transposed [n][k] ----
__global__ __launch_bounds__(256) void k_prep(
    const float* __restrict__ X,
    const float* __restrict__ Wq, const float* __restrict__ Wk,
    const float* __restrict__ Wv, const float* __restrict__ Wo,
    unsigned short* __restrict__ Xbf, unsigned short* __restrict__ Wt) {
  const int tid = blockIdx.x * 256 + threadIdx.x;
  const int NX4 = (8192 * 256) / 4;           // 524288 float4s of X
  if (tid < NX4) {
    float4 v = reinterpret_cast<const float4*>(X)[tid];
    ushort4 o;
    o.x = f2bf(v.x); o.y = f2bf(v.y); o.z = f2bf(v.z); o.w = f2bf(v.w);
    reinterpret_cast<ushort4*>(Xbf)[tid] = o;
  } else {
    int t = tid - NX4;                        // 0 .. 262143
    int mat = t >> 16;
    int e = t & 65535;
    int n = e >> 8, k = e & 255;              // output Wt[mat][n][k]
    const float* W = (mat == 0) ? Wq : (mat == 1) ? Wk : (mat == 2) ? Wv : Wo;
    Wt[t] = f2bf(W[k * 256 + n]);
  }
}

// ---------------- QKV projection GEMM -----------------------------------------
// grid (512, 3): x = m-tile of 16, y = matrix (0=Q 1=K 2=V). block 256 (4 waves),
// wave w covers 16 cols of each 64-col slab. Q pre-scaled by QSCALE.
__global__ __launch_bounds__(256, 2) void k_qkv(
    const unsigned short* __restrict__ Xbf, const unsigned short* __restrict__ Wt,
    const float* __restrict__ bq, const float* __restrict__ bk,
    const float* __restrict__ bv,
    unsigned short* __restrict__ Qb, unsigned short* __restrict__ Kb,
    unsigned short* __restrict__ Vt) {
  const int lane = threadIdx.x & 63;
  const int w = threadIdx.x >> 6;
  const int lr = lane & 15, lg = lane >> 4;
  const int m0 = blockIdx.x << 4;
  const int mat = blockIdx.y;

  bf16x8 a[8];
  #pragma unroll
  for (int ks = 0; ks < 8; ++ks)
    a[ks] = ldfrag(Xbf + (m0 + lr) * 256 + ks * 32 + lg * 8);

  const unsigned short* Wm = Wt + mat * 65536;
  const float* bias = (mat == 0) ? bq : (mat == 1) ? bk : bv;

  #pragma unroll
  for (int nb = 0; nb < 4; ++nb) {
    const int nloc = nb * 64 + w * 16;
    bf16x8 bfr[8];
    #pragma unroll
    for (int ks = 0; ks < 8; ++ks)
      bfr[ks] = ldfrag(Wm + (nloc + lr) * 256 + ks * 32 + lg * 8);
    f32x4 acc = {0.f, 0.f, 0.f, 0.f};
    #pragma unroll
    for (int ks = 0; ks < 8; ++ks)
      acc = mfma16(a[ks], bfr[ks], acc);
    const float bb = bias[nloc + lr];
    const int cm = nloc + lr;
    const int hh = cm >> 5, d = cm & 31;
    if (mat == 2) {                           // V transposed: 4 consecutive halfs
      ushort4 vv;
      unsigned short* vp = (unsigned short*)&vv;
      #pragma unroll
      for (int i = 0; i < 4; ++i) vp[i] = f2bf(acc[i] + bb);
      const int row = m0 + lg * 4;
      const int bidx = row >> 10, nn = row & 1023;
      *reinterpret_cast<ushort4*>(&Vt[(((bidx * 8 + hh) * 32) + d) * 1024 + nn]) = vv;
    } else if (mat == 0) {
      #pragma unroll
      for (int i = 0; i < 4; ++i) {
        const int row = m0 + lg * 4 + i;
        const int bidx = row >> 10, nn = row & 1023;
        Qb[(((bidx * 8 + hh) * 1024) + nn) * 32 + d] = f2bf((acc[i] + bb) * QSCALE);
      }
    } else {
      #pragma unroll
      for (int i = 0; i < 4; ++i) {
        const int row = m0 + lg * 4 + i;
        const int bidx = row >> 10, nn = row & 1023;
        Kb[(((bidx * 8 + hh) * 1024) + nn) * 32 + d] = f2bf(acc[i] + bb);
      }
    }
  }
}

// ---------------- fused masked attention --------------------------------------
// grid 4096: b = bi&7 (XCD-affine), h = (bi>>3)&7, q0 = (bi>>6)*16.
// block 256 = 4 waves; wave w covers keys [w*256, w*256+256) in 4 iters of 64.
// S^T (q in lanes) + O^T (O cols = q). Fixed-max softmax: p = exp2(s + c*D),
// masked -> exact 0; per-wave partial (o, psum) reduced via LDS at the end.
__global__ __launch_bounds__(256, 4) void k_attn(
    const unsigned short* __restrict__ Qb, const unsigned short* __restrict__ Kb,
    const unsigned short* __restrict__ Vt, const int* __restrict__ A,
    const float* __restrict__ D, const float* __restrict__ dsc,
    unsigned short* __restrict__ AO) {
  __shared__ unsigned short P[4][16][72];     // [wave][q][64 keys + pad]
  __shared__ float OB[4][64][12];             // [wave][lane][o0(4) o1(4) psum pad]
  const int lane = threadIdx.x & 63;
  const int w = threadIdx.x >> 6;
  const int lr = lane & 15, lg = lane >> 4;
  const int bi = blockIdx.x;
  const int b = bi & 7;                       // XCD affinity: batch b -> XCD b
  const int h = (bi >> 3) & 7;
  const int q0 = (bi >> 6) << 4;
  const float c = -dsc[0] * LOG2E;

  const unsigned short* Qh = Qb + (size_t)((b * 8 + h) * 1024) * 32;
  const unsigned short* Kh = Kb + (size_t)((b * 8 + h) * 1024) * 32;
  const unsigned short* Vh = Vt + (size_t)((b * 8 + h) * 32) * 1024;
  const int*   Arow = A + ((size_t)b << 20) + ((size_t)(q0 + lr) << 10);
  const float* Drow = D + ((size_t)b << 20) + ((size_t)(q0 + lr) << 10);

  const bf16x8 qf = ldfrag(Qh + (q0 + lr) * 32 + lg * 8);

  f32x4 o0 = {0.f, 0.f, 0.f, 0.f}, o1 = {0.f, 0.f, 0.f, 0.f};
  float psum = 0.f;

  for (int t = 0; t < 4; ++t) {
    const int k0 = (w << 8) + (t << 6);

    // loads for this tile (independent; rely on 16 waves/CU for MLP)
    bf16x8 kf[4], vf[2][2];
    i32x4 aa[4];
    f32x4 dd[4];
    #pragma unroll
    for (int st = 0; st < 4; ++st) {
      kf[st] = ldfrag(Kh + (k0 + st * 16 + lr) * 32 + lg * 8);
      aa[st] = *reinterpret_cast<const i32x4*>(Arow + k0 + st * 16 + lg * 4);
      dd[st] = *reinterpret_cast<const f32x4*>(Drow + k0 + st * 16 + lg * 4);
    }
    #pragma unroll
    for (int dh = 0; dh < 2; ++dh)
      #pragma unroll
      for (int ks = 0; ks < 2; ++ks)
        vf[dh][ks] = ldfrag(Vh + (dh * 16 + lr) * 1024 + k0 + ks * 32 + lg * 8);

    // QK^T: s[st] rows = keys k0+st*16+lg*4+i, cols = q (lane lr)
    const f32x4 zz = {0.f, 0.f, 0.f, 0.f};
    f32x4 s[4];
    #pragma unroll
    for (int st = 0; st < 4; ++st)
      s[st] = mfma16(kf[st], qf, zz);

    // p = exp2(s + c*D) (fixed max 0), masked -> exact 0; per-lane l accum
    float p[4][4];
    #pragma unroll
    for (int st = 0; st < 4; ++st)
      #pragma unroll
      for (int i = 0; i < 4; ++i) {
        const float pv = exp2f(s[st][i] + c * dd[st][i]);
        p[st][i] = (aa[st][i] <= 0) ? 0.0f : pv;
        psum += p[st][i];
      }

    // pack P -> LDS (transpose for PV B-fragment), read back, PV
    #pragma unroll
    for (int st = 0; st < 4; ++st) {
      bf16x4 pw;
      #pragma unroll
      for (int i = 0; i < 4; ++i) pw[i] = (__bf16)p[st][i];
      *reinterpret_cast<bf16x4*>(&P[w][lr][st * 16 + lg * 4]) = pw;
    }
    const unsigned short* pb = &P[w][lr][0];
    const bf16x8 pf0 = *reinterpret_cast<const bf16x8*>(pb + lg * 8);
    const bf16x8 pf1 = *reinterpret_cast<const bf16x8*>(pb + 32 + lg * 8);
    o0 = mfma16(vf[0][0], pf0, o0);
    o0 = mfma16(vf[0][1], pf1, o0);
    o1 = mfma16(vf[1][0], pf0, o1);
    o1 = mfma16(vf[1][1], pf1, o1);
  }

  // cross-wave reduction of (o0, o1, psum)
  #pragma unroll
  for (int i = 0; i < 4; ++i) {
    OB[w][lane][i] = o0[i];
    OB[w][lane][4 + i] = o1[i];
  }
  OB[w][lane][8] = psum;
  __syncthreads();

  if (w == 0) {
    f32x4 a0 = {0.f, 0.f, 0.f, 0.f}, a1 = {0.f, 0.f, 0.f, 0.f};
    float ls = 0.f;
    #pragma unroll
    for (int ww = 0; ww < 4; ++ww) {
      const f32x4 t0 = *reinterpret_cast<const f32x4*>(&OB[ww][lane][0]);
      const f32x4 t1 = *reinterpret_cast<const f32x4*>(&OB[ww][lane][4]);
      #pragma unroll
      for (int i = 0; i < 4; ++i) { a0[i] += t0[i]; a1[i] += t1[i]; }
      ls += OB[ww][lane][8];
    }
    ls += __shfl_xor(ls, 16);
    ls += __shfl_xor(ls, 32);
    const float linv = 1.0f / ls;             // per-lane (q = lr)

    ushort4 r0, r1;
    unsigned short* r0p = (unsigned short*)&r0;
    unsigned short* r1p = (unsigned short*)&r1;
    #pragma unroll
    for (int i = 0; i < 4; ++i) {
      r0p[i] = f2bf(a0[i] * linv);
      r1p[i] = f2bf(a1[i] * linv);
    }
    const int row = (b << 10) + q0 + lr;
    *reinterpret_cast<ushort4*>(&AO[row * 256 + h * 32 + lg * 4]) = r0;
    *reinterpret_cast<ushort4*>(&AO[row * 256 + h * 32 + 16 + lg * 4]) = r1;
  }
}

// ---------------- output projection -------------------------------------------
// grid (512, 2): x = m-tile of 16, y = 128-col half.
__global__ __launch_bounds__(256, 2) void k_oproj(
    const unsigned short* __restrict__ AO, const unsigned short* __restrict__ Wto,
    const float* __restrict__ bo, float* __restrict__ out) {
  const int lane = threadIdx.x & 63;
  const int w = threadIdx.x >> 6;
  const int lr = lane & 15, lg = lane >> 4;
  const int m0 = blockIdx.x << 4;

  bf16x8 a[8];
  #pragma unroll
  for (int ks = 0; ks < 8; ++ks)
    a[ks] = ldfrag(AO + (m0 + lr) * 256 + ks * 32 + lg * 8);

  #pragma unroll
  for (int j = 0; j < 2; ++j) {
    const int c0 = (blockIdx.y * 2 + j) * 64 + w * 16;
    bf16x8 bfr[8];
    #pragma unroll
    for (int ks = 0; ks < 8; ++ks)
      bfr[ks] = ldfrag(Wto + (c0 + lr) * 256 + ks * 32 + lg * 8);
    f32x4 acc = {0.f, 0.f, 0.f, 0.f};
    #pragma unroll
    for (int ks = 0; ks < 8; ++ks)
      acc = mfma16(a[ks], bfr[ks], acc);
    const float bb = bo[c0 + lr];
    #pragma unroll
    for (int i = 0; i < 4; ++i) {
      const int row = m0 + lg * 4 + i;
      out[row * 256 + c0 + lr] = acc[i] + bb;
    }
  }
}

extern "C" void kernel_launch(void* const* d_in, const int* in_sizes, int n_in,
                              void* d_out, int out_size, void* d_ws, size_t ws_size,
                              hipStream_t stream) {
  const float* X   = (const float*)d_in[0];
  const int*   A   = (const int*)d_in[1];
  const float* D   = (const float*)d_in[2];
  const float* Wq  = (const float*)d_in[3];
  const float* bq  = (const float*)d_in[4];
  const float* Wk  = (const float*)d_in[5];
  const float* bk  = (const float*)d_in[6];
  const float* Wv  = (const float*)d_in[7];
  const float* bv  = (const float*)d_in[8];
  const float* Wo  = (const float*)d_in[9];
  const float* bo  = (const float*)d_in[10];
  const float* dsc = (const float*)d_in[11];
  float* out = (float*)d_out;

  unsigned short* ws = (unsigned short*)d_ws;
  unsigned short* Xbf  = ws;                   // 2,097,152  (reused as AO later)
  unsigned short* Wt   = ws + 2097152;         //   262,144
  unsigned short* Qb   = ws + 2359296;         // 2,097,152
  unsigned short* Kb   = ws + 4456448;         // 2,097,152
  unsigned short* Vt   = ws + 6553600;         // 2,097,152  (total ~17.3 MB)
  unsigned short* AO   = Xbf;                  // alias: Xbf dead after k_qkv

  hipLaunchKernelGGL(k_prep, dim3(3072), dim3(256), 0, stream,
                     X, Wq, Wk, Wv, Wo, Xbf, Wt);
  hipLaunchKernelGGL(k_qkv, dim3(512, 3), dim3(256), 0, stream,
                     Xbf, Wt, bq, bk, bv, Qb, Kb, Vt);
  hipLaunchKernelGGL(k_attn, dim3(4096), dim3(256), 0, stream,
                     Qb, Kb, Vt, A, D, dsc, AO);
  hipLaunchKernelGGL(k_oproj, dim3(512, 2), dim3(256), 0, stream,
                     AO, Wt + 196608, bo, out);
}